// Round 1
// baseline (569.526 us; speedup 1.0000x reference)
//
#include <hip/hip_runtime.h>
#include <hip/hip_bf16.h>

typedef __attribute__((ext_vector_type(8))) short short8;
typedef __attribute__((ext_vector_type(4))) short short4v;
typedef __attribute__((ext_vector_type(4))) float f32x4;
typedef __bf16 bf16x8 __attribute__((ext_vector_type(8)));

#define DEVI static __device__ __forceinline__

DEVI short f2bs(float f) {
    union { __hip_bfloat16 h; short s; } u;
    u.h = __float2bfloat16(f);
    return u.s;
}

DEVI f32x4 mfma16(short8 a, short8 b, f32x4 c) {
    return __builtin_amdgcn_mfma_f32_16x16x32_bf16(
        __builtin_bit_cast(bf16x8, a), __builtin_bit_cast(bf16x8, b), c, 0, 0, 0);
}

// C[m][n] = sum_k A[m][k] * W[n][k], M=8192, N=1024, K=1024.
// MODE 0: A fp32, out bf16 at [B=4,H=16,S=2048,64]   (Q,K projections)
// MODE 1: A fp32, out bf16 transposed [B,H,64,S]     (V projection)
// MODE 2: A bf16 (ws), out fp32 row-major [8192,1024] (final proj)
template <int MODE>
__global__ __launch_bounds__(256) void gemm128(const void* __restrict__ Ag,
                                               const float* __restrict__ Wg,
                                               void* __restrict__ outp) {
    __shared__ __align__(16) short smem[2 * 128 * 72];
    short* As = smem;
    short* Bs = smem + 128 * 72;

    const int t = threadIdx.x;
    const int lane = t & 63, w = t >> 6;
    const int col = lane & 15, quad = lane >> 4;
    const int wm = (w & 1) * 64, wn = (w >> 1) * 64;
    const int m0 = blockIdx.y * 128, n0 = blockIdx.x * 128;

    f32x4 acc[4][4];
#pragma unroll
    for (int i = 0; i < 4; ++i)
#pragma unroll
        for (int j = 0; j < 4; ++j) acc[i][j] = (f32x4){0.f, 0.f, 0.f, 0.f};

    for (int kt = 0; kt < 16; ++kt) {
        const int k0 = kt * 64;
        if (MODE < 2) {
            const float* A = (const float*)Ag;
#pragma unroll
            for (int i = 0; i < 8; ++i) {
                int c = t + 256 * i;
                int row = c >> 4, cc = (c & 15) * 4;
                const float4 v = *(const float4*)(A + (size_t)(m0 + row) * 1024 + k0 + cc);
                short4v sv;
                sv.x = f2bs(v.x); sv.y = f2bs(v.y); sv.z = f2bs(v.z); sv.w = f2bs(v.w);
                *(short4v*)(As + row * 72 + cc) = sv;
            }
        } else {
            const short* A = (const short*)Ag;
#pragma unroll
            for (int i = 0; i < 4; ++i) {
                int c = t + 256 * i;
                int row = c >> 3, cc = (c & 7) * 8;
                *(short8*)(As + row * 72 + cc) =
                    *(const short8*)(A + (size_t)(m0 + row) * 1024 + k0 + cc);
            }
        }
#pragma unroll
        for (int i = 0; i < 8; ++i) {
            int c = t + 256 * i;
            int row = c >> 4, cc = (c & 15) * 4;
            const float4 v = *(const float4*)(Wg + (size_t)(n0 + row) * 1024 + k0 + cc);
            short4v sv;
            sv.x = f2bs(v.x); sv.y = f2bs(v.y); sv.z = f2bs(v.z); sv.w = f2bs(v.w);
            *(short4v*)(Bs + row * 72 + cc) = sv;
        }
        __syncthreads();
#pragma unroll
        for (int ks = 0; ks < 2; ++ks) {
            short8 a[4], b[4];
#pragma unroll
            for (int i = 0; i < 4; ++i)
                a[i] = *(const short8*)(As + (wm + i * 16 + col) * 72 + ks * 32 + quad * 8);
#pragma unroll
            for (int i = 0; i < 4; ++i)
                b[i] = *(const short8*)(Bs + (wn + i * 16 + col) * 72 + ks * 32 + quad * 8);
#pragma unroll
            for (int mi = 0; mi < 4; ++mi)
#pragma unroll
                for (int ni = 0; ni < 4; ++ni)
                    acc[mi][ni] = mfma16(a[mi], b[ni], acc[mi][ni]);
        }
        __syncthreads();
    }

    if (MODE == 0) {
        short* outs = (short*)outp;
#pragma unroll
        for (int mi = 0; mi < 4; ++mi)
#pragma unroll
            for (int ni = 0; ni < 4; ++ni)
#pragma unroll
                for (int r = 0; r < 4; ++r) {
                    int m = m0 + wm + mi * 16 + quad * 4 + r;   // b*2048+s
                    int n = n0 + wn + ni * 16 + col;            // h*64+kk
                    size_t off = ((size_t)((m >> 11) * 16 + (n >> 6)) * 2048 + (m & 2047)) * 64 +
                                 (n & 63);
                    outs[off] = f2bs(acc[mi][ni][r]);
                }
    } else if (MODE == 1) {
        // transpose through LDS, store vpt[(b*1024+n)*2048 + s]
        short* T = smem;  // [128 n][132 m]
#pragma unroll
        for (int mi = 0; mi < 4; ++mi)
#pragma unroll
            for (int ni = 0; ni < 4; ++ni) {
                int n_l = wn + ni * 16 + col;
                int m_l = wm + mi * 16 + quad * 4;
                short4v sv;
                sv.x = f2bs(acc[mi][ni][0]); sv.y = f2bs(acc[mi][ni][1]);
                sv.z = f2bs(acc[mi][ni][2]); sv.w = f2bs(acc[mi][ni][3]);
                *(short4v*)(T + n_l * 132 + m_l) = sv;
            }
        __syncthreads();
        short* outs = (short*)outp;
        int nrow = t >> 1, mh = (t & 1) * 64;
        int b = m0 >> 11, s0 = m0 & 2047;
        size_t base = ((size_t)(b * 1024 + n0 + nrow)) * 2048 + s0 + mh;
#pragma unroll
        for (int j = 0; j < 16; ++j) {
            unsigned long long vv = *(const unsigned long long*)(T + nrow * 132 + mh + j * 4);
            *(unsigned long long*)(outs + base + j * 4) = vv;
        }
    } else {
        float* outf = (float*)outp;
#pragma unroll
        for (int mi = 0; mi < 4; ++mi)
#pragma unroll
            for (int ni = 0; ni < 4; ++ni)
#pragma unroll
                for (int r = 0; r < 4; ++r) {
                    int m = m0 + wm + mi * 16 + quad * 4 + r;
                    int n = n0 + wn + ni * 16 + col;
                    outf[(size_t)m * 1024 + n] = acc[mi][ni][r];
                }
    }
}

// Flash attention: qp,kp [BH][2048][64] bf16; vpt [BH][64][2048] bf16;
// ao [B][S][1024] bf16. Grid (16 q-tiles, 64 bh), 256 threads (4 waves, 32 q-rows each).
__global__ __launch_bounds__(256) void flash_attn(const short* __restrict__ qp,
                                                  const short* __restrict__ kp,
                                                  const short* __restrict__ vpt,
                                                  short* __restrict__ ao) {
    __shared__ __align__(16) short Qs[128 * 72];
    __shared__ __align__(16) short Ks[128 * 72];
    __shared__ __align__(16) short Ps[4 * 32 * 136];

    const int t = threadIdx.x, lane = t & 63, w = t >> 6;
    const int col = lane & 15, quad = lane >> 4;
    const int bh = blockIdx.y, q0 = blockIdx.x * 128;
    const short* qb = qp + (size_t)bh * 2048 * 64;
    const short* kb = kp + (size_t)bh * 2048 * 64;
    const short* vb = vpt + (size_t)bh * 64 * 2048;

#pragma unroll
    for (int i = 0; i < 4; ++i) {
        int c = t + 256 * i;
        int row = c >> 3, cc = (c & 7) * 8;
        *(short8*)(Qs + row * 72 + cc) = *(const short8*)(qb + (size_t)(q0 + row) * 64 + cc);
    }

    f32x4 acc_o[2][4];
    float m_r[2][4], l_r[2][4];
#pragma unroll
    for (int mi = 0; mi < 2; ++mi) {
#pragma unroll
        for (int ni = 0; ni < 4; ++ni) acc_o[mi][ni] = (f32x4){0.f, 0.f, 0.f, 0.f};
#pragma unroll
        for (int r = 0; r < 4; ++r) { m_r[mi][r] = -1e30f; l_r[mi][r] = 0.f; }
    }

    short* Pw = Ps + w * (32 * 136);

    for (int kt = 0; kt < 16; ++kt) {
#pragma unroll
        for (int i = 0; i < 4; ++i) {
            int c = t + 256 * i;
            int row = c >> 3, cc = (c & 7) * 8;
            *(short8*)(Ks + row * 72 + cc) =
                *(const short8*)(kb + (size_t)(kt * 128 + row) * 64 + cc);
        }
        __syncthreads();

        // S = Q K^T
        f32x4 sc[2][8];
#pragma unroll
        for (int mi = 0; mi < 2; ++mi)
#pragma unroll
            for (int ni = 0; ni < 8; ++ni) sc[mi][ni] = (f32x4){0.f, 0.f, 0.f, 0.f};
#pragma unroll
        for (int ks = 0; ks < 2; ++ks) {
            short8 aq[2];
#pragma unroll
            for (int mi = 0; mi < 2; ++mi)
                aq[mi] = *(const short8*)(Qs + (w * 32 + mi * 16 + col) * 72 + ks * 32 + quad * 8);
#pragma unroll
            for (int ni = 0; ni < 8; ++ni) {
                short8 bk = *(const short8*)(Ks + (ni * 16 + col) * 72 + ks * 32 + quad * 8);
#pragma unroll
                for (int mi = 0; mi < 2; ++mi) sc[mi][ni] = mfma16(aq[mi], bk, sc[mi][ni]);
            }
        }

        // online softmax; rows = quad*4+r (per mi), cols spread over 16 lanes x 8 ni
#pragma unroll
        for (int mi = 0; mi < 2; ++mi) {
            float alpha[4];
#pragma unroll
            for (int r = 0; r < 4; ++r) {
                float v = -1e30f;
#pragma unroll
                for (int ni = 0; ni < 8; ++ni) {
                    sc[mi][ni][r] *= 0.125f;
                    v = fmaxf(v, sc[mi][ni][r]);
                }
                v = fmaxf(v, __shfl_xor(v, 1));
                v = fmaxf(v, __shfl_xor(v, 2));
                v = fmaxf(v, __shfl_xor(v, 4));
                v = fmaxf(v, __shfl_xor(v, 8));
                float mnew = fmaxf(m_r[mi][r], v);
                alpha[r] = __expf(m_r[mi][r] - mnew);
                m_r[mi][r] = mnew;
                float ls = 0.f;
#pragma unroll
                for (int ni = 0; ni < 8; ++ni) {
                    float p = __expf(sc[mi][ni][r] - mnew);
                    sc[mi][ni][r] = p;
                    ls += p;
                }
                ls += __shfl_xor(ls, 1);
                ls += __shfl_xor(ls, 2);
                ls += __shfl_xor(ls, 4);
                ls += __shfl_xor(ls, 8);
                l_r[mi][r] = l_r[mi][r] * alpha[r] + ls;
            }
#pragma unroll
            for (int ni = 0; ni < 4; ++ni)
#pragma unroll
                for (int r = 0; r < 4; ++r) acc_o[mi][ni][r] *= alpha[r];
            // P -> LDS (C-layout -> A-operand layout round trip)
#pragma unroll
            for (int ni = 0; ni < 8; ++ni)
#pragma unroll
                for (int r = 0; r < 4; ++r)
                    Pw[(mi * 16 + quad * 4 + r) * 136 + ni * 16 + col] = f2bs(sc[mi][ni][r]);
        }

        // O += P V  (V B-fragments straight from global vpt, key-contiguous)
#pragma unroll
        for (int ks = 0; ks < 4; ++ks) {
            short8 bv[4];
#pragma unroll
            for (int ni = 0; ni < 4; ++ni)
                bv[ni] = *(const short8*)(vb + (size_t)(ni * 16 + col) * 2048 + kt * 128 +
                                          ks * 32 + quad * 8);
#pragma unroll
            for (int mi = 0; mi < 2; ++mi) {
                short8 ap = *(const short8*)(Pw + (mi * 16 + col) * 136 + ks * 32 + quad * 8);
#pragma unroll
                for (int ni = 0; ni < 4; ++ni) acc_o[mi][ni] = mfma16(ap, bv[ni], acc_o[mi][ni]);
            }
        }
        __syncthreads();
    }

    const int b = bh >> 4, h = bh & 15;
#pragma unroll
    for (int mi = 0; mi < 2; ++mi)
#pragma unroll
        for (int ni = 0; ni < 4; ++ni)
#pragma unroll
            for (int r = 0; r < 4; ++r) {
                int q = q0 + w * 32 + mi * 16 + quad * 4 + r;
                float o = acc_o[mi][ni][r] / l_r[mi][r];
                ao[((size_t)(b * 2048 + q)) * 1024 + h * 64 + ni * 16 + col] = f2bs(o);
            }
}

extern "C" void kernel_launch(void* const* d_in, const int* in_sizes, int n_in,
                              void* d_out, int out_size, void* d_ws, size_t ws_size,
                              hipStream_t stream) {
    const float* q  = (const float*)d_in[0];
    const float* k  = (const float*)d_in[1];
    const float* v  = (const float*)d_in[2];
    const float* Wq = (const float*)d_in[3];
    const float* Wk = (const float*)d_in[4];
    const float* Wv = (const float*)d_in[5];
    const float* Wo = (const float*)d_in[6];
    float* out = (float*)d_out;

    short* ws = (short*)d_ws;
    const size_t SZ = (size_t)64 * 2048 * 64;  // 8,388,608 bf16 elements
    short* qp  = ws;
    short* kp  = ws + SZ;
    short* vpt = ws + 2 * SZ;
    short* ao  = ws + 3 * SZ;

    dim3 blk(256);
    gemm128<0><<<dim3(8, 64), blk, 0, stream>>>((const void*)q, Wq, (void*)qp);
    gemm128<0><<<dim3(8, 64), blk, 0, stream>>>((const void*)k, Wk, (void*)kp);
    gemm128<1><<<dim3(8, 64), blk, 0, stream>>>((const void*)v, Wv, (void*)vpt);
    flash_attn<<<dim3(16, 64), blk, 0, stream>>>(qp, kp, vpt, ao);
    gemm128<2><<<dim3(8, 64), blk, 0, stream>>>((const void*)ao, Wo, (void*)out);
}

// Round 2
// 499.658 us; speedup vs baseline: 1.1398x; 1.1398x over previous
//
#include <hip/hip_runtime.h>
#include <hip/hip_bf16.h>

typedef __attribute__((ext_vector_type(8))) short short8;
typedef __attribute__((ext_vector_type(4))) short short4v;
typedef __attribute__((ext_vector_type(4))) float f32x4;
typedef __bf16 bf16x8 __attribute__((ext_vector_type(8)));

#define DEVI static __device__ __forceinline__

DEVI short f2bs(float f) {
    union { __hip_bfloat16 h; short s; } u;
    u.h = __float2bfloat16(f);
    return u.s;
}

DEVI f32x4 mfma16(short8 a, short8 b, f32x4 c) {
    return __builtin_amdgcn_mfma_f32_16x16x32_bf16(
        __builtin_bit_cast(bf16x8, a), __builtin_bit_cast(bf16x8, b), c, 0, 0, 0);
}

// async global->LDS, 16B per lane; LDS dest = wave-uniform base + lane*16
DEVI void glds16(const short* g, short* l) {
    __builtin_amdgcn_global_load_lds((const __attribute__((address_space(1))) void*)g,
                                     (__attribute__((address_space(3))) void*)l, 16, 0, 0);
}

// fp32 -> bf16 converts (activations: 3 equal-size tensors)
__global__ __launch_bounds__(256) void cvt3(const float4* __restrict__ a,
                                            const float4* __restrict__ b,
                                            const float4* __restrict__ c,
                                            short4v* __restrict__ da,
                                            short4v* __restrict__ db,
                                            short4v* __restrict__ dc, int n4) {
    int i = blockIdx.x * 256 + threadIdx.x;
    if (i < n4) {
        float4 v;
        short4v s;
        v = a[i]; s.x = f2bs(v.x); s.y = f2bs(v.y); s.z = f2bs(v.z); s.w = f2bs(v.w); da[i] = s;
        v = b[i]; s.x = f2bs(v.x); s.y = f2bs(v.y); s.z = f2bs(v.z); s.w = f2bs(v.w); db[i] = s;
        v = c[i]; s.x = f2bs(v.x); s.y = f2bs(v.y); s.z = f2bs(v.z); s.w = f2bs(v.w); dc[i] = s;
    }
}

__global__ __launch_bounds__(256) void cvt4(const float4* __restrict__ a,
                                            const float4* __restrict__ b,
                                            const float4* __restrict__ c,
                                            const float4* __restrict__ d,
                                            short4v* __restrict__ da,
                                            short4v* __restrict__ db,
                                            short4v* __restrict__ dc,
                                            short4v* __restrict__ dd, int n4) {
    int i = blockIdx.x * 256 + threadIdx.x;
    if (i < n4) {
        float4 v;
        short4v s;
        v = a[i]; s.x = f2bs(v.x); s.y = f2bs(v.y); s.z = f2bs(v.z); s.w = f2bs(v.w); da[i] = s;
        v = b[i]; s.x = f2bs(v.x); s.y = f2bs(v.y); s.z = f2bs(v.z); s.w = f2bs(v.w); db[i] = s;
        v = c[i]; s.x = f2bs(v.x); s.y = f2bs(v.y); s.z = f2bs(v.z); s.w = f2bs(v.w); dc[i] = s;
        v = d[i]; s.x = f2bs(v.x); s.y = f2bs(v.y); s.z = f2bs(v.z); s.w = f2bs(v.w); dd[i] = s;
    }
}

// C[m][n] = sum_k A[m][k]*B[n][k]; A bf16 [8192][1024], B bf16 [1024][1024].
// Staged via global_load_lds w/ xor swizzle: slot = row*8 + (kc ^ (row&7)).
// MODE 0: out bf16 [B,H,S,64] (*scale)   MODE 1: out bf16 transposed [B,H,64,S]
// MODE 2: out fp32 row-major [8192][1024]
template <int MODE>
__global__ __launch_bounds__(256) void gemm_glds(const short* __restrict__ A,
                                                 const short* __restrict__ Bw,
                                                 void* __restrict__ outp, float scale) {
    __shared__ __align__(16) short smem[16896];  // As[8192] Bs[8192] | T[128*132]
    short* As = smem;
    short* Bs = smem + 8192;

    const int t = threadIdx.x;
    const int lane = t & 63, w = t >> 6;
    const int col = lane & 15, quad = lane >> 4;
    const int wm = (w & 1) * 64, wn = (w >> 1) * 64;
    const int m0 = blockIdx.y * 128, n0 = blockIdx.x * 128;

    f32x4 acc[4][4];
#pragma unroll
    for (int i = 0; i < 4; ++i)
#pragma unroll
        for (int j = 0; j < 4; ++j) acc[i][j] = (f32x4){0.f, 0.f, 0.f, 0.f};

    for (int kt = 0; kt < 16; ++kt) {
        const int k0 = kt * 64;
#pragma unroll
        for (int j = 0; j < 4; ++j) {
            int cbase = (j * 4 + w) * 64;
            int c = cbase + lane;
            int row = c >> 3, kc = (c & 7) ^ (row & 7);
            glds16(A + (size_t)(m0 + row) * 1024 + k0 + kc * 8, As + cbase * 8);
        }
#pragma unroll
        for (int j = 0; j < 4; ++j) {
            int cbase = (j * 4 + w) * 64;
            int c = cbase + lane;
            int row = c >> 3, kc = (c & 7) ^ (row & 7);
            glds16(Bw + (size_t)(n0 + row) * 1024 + k0 + kc * 8, Bs + cbase * 8);
        }
        __syncthreads();
#pragma unroll
        for (int ks = 0; ks < 2; ++ks) {
            short8 a[4], b[4];
#pragma unroll
            for (int i = 0; i < 4; ++i) {
                int row = wm + i * 16 + col;
                int kc = (ks * 4 + quad) ^ (col & 7);
                a[i] = *(const short8*)(As + (row * 8 + kc) * 8);
            }
#pragma unroll
            for (int i = 0; i < 4; ++i) {
                int row = wn + i * 16 + col;
                int kc = (ks * 4 + quad) ^ (col & 7);
                b[i] = *(const short8*)(Bs + (row * 8 + kc) * 8);
            }
#pragma unroll
            for (int mi = 0; mi < 4; ++mi)
#pragma unroll
                for (int ni = 0; ni < 4; ++ni)
                    acc[mi][ni] = mfma16(a[mi], b[ni], acc[mi][ni]);
        }
        __syncthreads();
    }

    if (MODE == 0) {
        short* outs = (short*)outp;
#pragma unroll
        for (int mi = 0; mi < 4; ++mi)
#pragma unroll
            for (int ni = 0; ni < 4; ++ni)
#pragma unroll
                for (int r = 0; r < 4; ++r) {
                    int m = m0 + wm + mi * 16 + quad * 4 + r;   // b*2048+s
                    int n = n0 + wn + ni * 16 + col;            // h*64+kk
                    size_t off = ((size_t)((m >> 11) * 16 + (n >> 6)) * 2048 + (m & 2047)) * 64 +
                                 (n & 63);
                    outs[off] = f2bs(acc[mi][ni][r] * scale);
                }
    } else if (MODE == 1) {
        short* T = smem;  // [128 n][132 m]
#pragma unroll
        for (int mi = 0; mi < 4; ++mi)
#pragma unroll
            for (int ni = 0; ni < 4; ++ni) {
                int n_l = wn + ni * 16 + col;
                int m_l = wm + mi * 16 + quad * 4;
                short4v sv;
                sv.x = f2bs(acc[mi][ni][0]); sv.y = f2bs(acc[mi][ni][1]);
                sv.z = f2bs(acc[mi][ni][2]); sv.w = f2bs(acc[mi][ni][3]);
                *(short4v*)(T + n_l * 132 + m_l) = sv;
            }
        __syncthreads();
        short* outs = (short*)outp;
        int nrow = t >> 1, mh = (t & 1) * 64;
        int b = m0 >> 11, s0 = m0 & 2047;
        size_t base = ((size_t)(b * 1024 + n0 + nrow)) * 2048 + s0 + mh;
#pragma unroll
        for (int j = 0; j < 16; ++j) {
            unsigned long long vv = *(const unsigned long long*)(T + nrow * 132 + mh + j * 4);
            *(unsigned long long*)(outs + base + j * 4) = vv;
        }
    } else {
        float* outf = (float*)outp;
#pragma unroll
        for (int mi = 0; mi < 4; ++mi)
#pragma unroll
            for (int ni = 0; ni < 4; ++ni)
#pragma unroll
                for (int r = 0; r < 4; ++r) {
                    int m = m0 + wm + mi * 16 + quad * 4 + r;
                    int n = n0 + wn + ni * 16 + col;
                    outf[(size_t)m * 1024 + n] = acc[mi][ni][r];
                }
    }
}

// Flash attention. qp (prescaled by 0.125*log2e), kp: [BH][2048][64] bf16;
// vpt [BH][64][2048] bf16; ao [B][S][1024] bf16.
// Grid (bh=64, qtile=16) so all q-tiles of one bh share an XCD. 256 thr, 4 waves.
__global__ __launch_bounds__(256) void flash_attn(const short* __restrict__ qp,
                                                  const short* __restrict__ kp,
                                                  const short* __restrict__ vpt,
                                                  short* __restrict__ ao) {
    __shared__ __align__(16) short Ks[128 * 64];     // 16 KB, swizzled
    __shared__ __align__(16) short Us[4 * 32 * 72];  // Q staging (8192) then per-wave P

    const int t = threadIdx.x, lane = t & 63, w = t >> 6;
    const int col = lane & 15, quad = lane >> 4;
    const int bh = blockIdx.x, q0 = blockIdx.y * 128;
    const short* qb = qp + (size_t)bh * 2048 * 64;
    const short* kb = kp + (size_t)bh * 2048 * 64;
    const short* vb = vpt + (size_t)bh * 64 * 2048;

    // stage Q tile (swizzled) and pull fragments to registers
#pragma unroll
    for (int j = 0; j < 4; ++j) {
        int cbase = (j * 4 + w) * 64;
        int c = cbase + lane;
        int row = c >> 3, kc = (c & 7) ^ (row & 7);
        glds16(qb + (size_t)(q0 + row) * 64 + kc * 8, Us + cbase * 8);
    }
    __syncthreads();
    short8 aq[2][2];
#pragma unroll
    for (int mi = 0; mi < 2; ++mi)
#pragma unroll
        for (int ks = 0; ks < 2; ++ks) {
            int row = w * 32 + mi * 16 + col;
            int kc = (ks * 4 + quad) ^ (col & 7);
            aq[mi][ks] = *(const short8*)(Us + (row * 8 + kc) * 8);
        }
    __syncthreads();

    f32x4 acc_o[2][4];
    float m_r[2][4], l_r[2][4];
#pragma unroll
    for (int mi = 0; mi < 2; ++mi) {
#pragma unroll
        for (int ni = 0; ni < 4; ++ni) acc_o[mi][ni] = (f32x4){0.f, 0.f, 0.f, 0.f};
#pragma unroll
        for (int r = 0; r < 4; ++r) { m_r[mi][r] = -1e30f; l_r[mi][r] = 0.f; }
    }

    short* Pw = Us + w * (32 * 72);

    for (int kt = 0; kt < 16; ++kt) {
#pragma unroll
        for (int j = 0; j < 4; ++j) {
            int cbase = (j * 4 + w) * 64;
            int c = cbase + lane;
            int row = c >> 3, kc = (c & 7) ^ (row & 7);
            glds16(kb + (size_t)(kt * 128 + row) * 64 + kc * 8, Ks + cbase * 8);
        }
        __syncthreads();

        // S = Q K^T (Q prescaled so S is already in scaled-log2 units)
        f32x4 sc[2][8];
#pragma unroll
        for (int mi = 0; mi < 2; ++mi)
#pragma unroll
            for (int ni = 0; ni < 8; ++ni) sc[mi][ni] = (f32x4){0.f, 0.f, 0.f, 0.f};
#pragma unroll
        for (int ks = 0; ks < 2; ++ks) {
#pragma unroll
            for (int ni = 0; ni < 8; ++ni) {
                int row = ni * 16 + col;
                int kc = (ks * 4 + quad) ^ (col & 7);
                short8 bk = *(const short8*)(Ks + (row * 8 + kc) * 8);
#pragma unroll
                for (int mi = 0; mi < 2; ++mi) sc[mi][ni] = mfma16(aq[mi][ks], bk, sc[mi][ni]);
            }
        }

        // online softmax in exp2 domain
#pragma unroll
        for (int mi = 0; mi < 2; ++mi) {
            float alpha[4];
#pragma unroll
            for (int r = 0; r < 4; ++r) {
                float v = -1e30f;
#pragma unroll
                for (int ni = 0; ni < 8; ++ni) v = fmaxf(v, sc[mi][ni][r]);
                v = fmaxf(v, __shfl_xor(v, 1));
                v = fmaxf(v, __shfl_xor(v, 2));
                v = fmaxf(v, __shfl_xor(v, 4));
                v = fmaxf(v, __shfl_xor(v, 8));
                float mnew = fmaxf(m_r[mi][r], v);
                alpha[r] = exp2f(m_r[mi][r] - mnew);
                m_r[mi][r] = mnew;
                float ls = 0.f;
#pragma unroll
                for (int ni = 0; ni < 8; ++ni) {
                    float p = exp2f(sc[mi][ni][r] - mnew);
                    sc[mi][ni][r] = p;
                    ls += p;
                }
                ls += __shfl_xor(ls, 1);
                ls += __shfl_xor(ls, 2);
                ls += __shfl_xor(ls, 4);
                ls += __shfl_xor(ls, 8);
                l_r[mi][r] = l_r[mi][r] * alpha[r] + ls;
            }
#pragma unroll
            for (int ni = 0; ni < 4; ++ni)
#pragma unroll
                for (int r = 0; r < 4; ++r) acc_o[mi][ni][r] *= alpha[r];
        }

        // O += P V in two 64-wide k halves (P per-wave LDS round trip)
#pragma unroll
        for (int ph = 0; ph < 2; ++ph) {
#pragma unroll
            for (int mi = 0; mi < 2; ++mi)
#pragma unroll
                for (int cw = 0; cw < 4; ++cw)
#pragma unroll
                    for (int r = 0; r < 4; ++r)
                        Pw[(mi * 16 + quad * 4 + r) * 72 + cw * 16 + col] =
                            f2bs(sc[mi][ph * 4 + cw][r]);
#pragma unroll
            for (int ks = 0; ks < 2; ++ks) {
                short8 bv[4];
#pragma unroll
                for (int ni = 0; ni < 4; ++ni)
                    bv[ni] = *(const short8*)(vb + (size_t)(ni * 16 + col) * 2048 + kt * 128 +
                                              ph * 64 + ks * 32 + quad * 8);
#pragma unroll
                for (int mi = 0; mi < 2; ++mi) {
                    short8 ap = *(const short8*)(Pw + (mi * 16 + col) * 72 + ks * 32 + quad * 8);
#pragma unroll
                    for (int ni = 0; ni < 4; ++ni)
                        acc_o[mi][ni] = mfma16(ap, bv[ni], acc_o[mi][ni]);
                }
            }
        }
        __syncthreads();
    }

    const int b = bh >> 4, hd = bh & 15;
#pragma unroll
    for (int mi = 0; mi < 2; ++mi)
#pragma unroll
        for (int ni = 0; ni < 4; ++ni)
#pragma unroll
            for (int r = 0; r < 4; ++r) {
                int q = q0 + w * 32 + mi * 16 + quad * 4 + r;
                float o = acc_o[mi][ni][r] / l_r[mi][r];
                ao[((size_t)(b * 2048 + q)) * 1024 + hd * 64 + ni * 16 + col] = f2bs(o);
            }
}

extern "C" void kernel_launch(void* const* d_in, const int* in_sizes, int n_in,
                              void* d_out, int out_size, void* d_ws, size_t ws_size,
                              hipStream_t stream) {
    const float* q  = (const float*)d_in[0];
    const float* k  = (const float*)d_in[1];
    const float* v  = (const float*)d_in[2];
    const float* Wq = (const float*)d_in[3];
    const float* Wk = (const float*)d_in[4];
    const float* Wv = (const float*)d_in[5];
    const float* Wo = (const float*)d_in[6];
    float* out = (float*)d_out;

    short* ws = (short*)d_ws;
    const size_t SZ = (size_t)64 * 2048 * 64;  // 8,388,608
    const size_t WZ = (size_t)1024 * 1024;     // 1,048,576
    // region plan (aliasing): r1: xq -> ao ; r2: xk -> vpt ; r3: xv ; qp ; kp ; 4 weights
    short* xq  = ws;               // later: ao
    short* xk  = ws + SZ;          // later: vpt
    short* xv  = ws + 2 * SZ;
    short* qp  = ws + 3 * SZ;
    short* kp  = ws + 4 * SZ;
    short* wqb = ws + 5 * SZ;
    short* wkb = wqb + WZ;
    short* wvb = wqb + 2 * WZ;
    short* wob = wqb + 3 * WZ;
    short* ao  = xq;
    short* vpt = xk;

    const float QSCALE = 0.125f * 1.44269504088896f;  // 1/sqrt(64) * log2(e)

    cvt3<<<dim3(8192), dim3(256), 0, stream>>>((const float4*)q, (const float4*)k,
                                               (const float4*)v, (short4v*)xq, (short4v*)xk,
                                               (short4v*)xv, (int)(SZ / 4));
    cvt4<<<dim3(1024), dim3(256), 0, stream>>>((const float4*)Wq, (const float4*)Wk,
                                               (const float4*)Wv, (const float4*)Wo,
                                               (short4v*)wqb, (short4v*)wkb, (short4v*)wvb,
                                               (short4v*)wob, (int)(WZ / 4));
    dim3 blk(256);
    gemm_glds<0><<<dim3(8, 64), blk, 0, stream>>>(xq, wqb, (void*)qp, QSCALE);
    gemm_glds<0><<<dim3(8, 64), blk, 0, stream>>>(xk, wkb, (void*)kp, 1.0f);
    gemm_glds<1><<<dim3(8, 64), blk, 0, stream>>>(xv, wvb, (void*)vpt, 1.0f);
    flash_attn<<<dim3(64, 16), blk, 0, stream>>>(qp, kp, vpt, ao);
    gemm_glds<2><<<dim3(8, 64), blk, 0, stream>>>(ao, wob, (void*)out, 1.0f);
}